// Round 6
// baseline (158.875 us; speedup 1.0000x reference)
//
#include <hip/hip_runtime.h>
#include <math.h>

#define VOCAB   50257
#define EMBED   256
#define NFREQ   64
#define NRULES  100
#define NTOK    4096        // B*S
#define CAP     256         // max tokens per rule (mean 41, sd 6.4; P(>256)~0)
#define ETILE   64          // e-columns per apply block
#define TTILE   48          // tokens per LDS tile (48 KB -> 3 blocks/CU)
#define TPG     (TTILE / 4) // 12 tokens per thread per tile

// ---- workspace layout ----
// [0)                 : base   float[NTOK][EMBED]  (4 MB)
// [BASE_BYTES)        : counts int[NRULES]
// [BASE_BYTES+512)    : list   int[NRULES][CAP]    (100 KB)
// [BASE_BYTES+103424) : wT     float[NFREQ][EMBED] (64 KB)
#define BASE_BYTES ((size_t)NTOK * EMBED * 4)
#define LIST_BYTES ((size_t)NRULES * CAP * 4)

// ---- k0: transpose proj_w -> wT[f][d], zero counts. 4 blocks. ----
__global__ __launch_bounds__(256) void prep_kernel(
    const float* __restrict__ proj_w,   // [EMBED][NFREQ]
    float*       __restrict__ wT,       // [NFREQ][EMBED]
    int*         __restrict__ counts)   // [NRULES]
{
    __shared__ float s_t[64 * 65];      // padded transpose tile
    const int tid = threadIdx.x;
    const int b   = blockIdx.x;         // d-tile: rows [64b, 64b+64)

    if (b == 0 && tid < NRULES) counts[tid] = 0;

    const float4* __restrict__ W4 =
        (const float4*)(proj_w + (size_t)b * 64 * NFREQ);
    #pragma unroll
    for (int i = 0; i < 4; ++i) {
        const int v = i * 256 + tid;
        const float4 w = W4[v];         // coalesced b128
        const int dl = v >> 4, f0 = (v & 15) * 4;
        s_t[dl * 65 + f0 + 0] = w.x;
        s_t[dl * 65 + f0 + 1] = w.y;
        s_t[dl * 65 + f0 + 2] = w.z;
        s_t[dl * 65 + f0 + 3] = w.w;
    }
    __syncthreads();
    #pragma unroll
    for (int j = 0; j < 16; ++j) {
        const int o = j * 256 + tid;
        const int f = o >> 6, c = o & 63;
        wT[f * EMBED + b * 64 + c] = s_t[c * 65 + f];   // coalesced out
    }
}

// ---- k1: fourier + projection + bucketing. 1024 blocks x 256 thr ----
__global__ __launch_bounds__(256) void fused_base_kernel(
    const int*   __restrict__ token_ids,     // [NTOK]
    const float* __restrict__ a_n,           // [VOCAB][NFREQ]
    const float* __restrict__ b_n,           // [VOCAB][NFREQ]
    const int*   __restrict__ token_rules,   // [VOCAB]
    const float* __restrict__ wT,            // [NFREQ][EMBED] (ws)
    const float* __restrict__ proj_b,        // [EMBED]
    float*       __restrict__ base,          // [NTOK][EMBED] (ws)
    int*         __restrict__ counts,        // [NRULES] (ws, zeroed by prep)
    int*         __restrict__ list)          // [NRULES][CAP] (ws)
{
    __shared__ float s_four[4][NFREQ];       // 1 KB

    const int tid = threadIdx.x;
    const int tl  = tid >> 6;                // token 0..3
    const int f   = tid & 63;                // frequency lane
    const int tok_idx = blockIdx.x * 4 + tl;
    const int tok     = token_ids[tok_idx];

    const float x = (float)tok / (float)VOCAB;
    float sv, cv;
    sincosf(6.283185307179586f * x * (float)(f + 1), &sv, &cv);
    s_four[tl][f] = a_n[(size_t)tok * NFREQ + f] * cv
                  + b_n[(size_t)tok * NFREQ + f] * sv;   // coalesced gathers

    if (f == 0) {
        const int rule = token_rules[tok];
        const int pos  = atomicAdd(&counts[rule], 1);
        if (pos < CAP) list[rule * CAP + pos] = tok_idx;
    }
    __syncthreads();

    const int   d    = tid;
    const float bias = proj_b[d];
    float a0 = bias, a1 = bias, a2 = bias, a3 = bias;

    #pragma unroll 4
    for (int q = 0; q < 16; ++q) {
        const float w0 = wT[(4 * q + 0) * EMBED + d];   // coalesced, L2-hot
        const float w1 = wT[(4 * q + 1) * EMBED + d];
        const float w2 = wT[(4 * q + 2) * EMBED + d];
        const float w3 = wT[(4 * q + 3) * EMBED + d];
        const float4 f0 = ((const float4*)s_four[0])[q];
        const float4 f1 = ((const float4*)s_four[1])[q];
        const float4 f2 = ((const float4*)s_four[2])[q];
        const float4 f3 = ((const float4*)s_four[3])[q];
        a0 += w0 * f0.x + w1 * f0.y + w2 * f0.z + w3 * f0.w;
        a1 += w0 * f1.x + w1 * f1.y + w2 * f1.z + w3 * f1.w;
        a2 += w0 * f2.x + w1 * f2.y + w2 * f2.z + w3 * f2.w;
        a3 += w0 * f3.x + w1 * f3.y + w2 * f3.z + w3 * f3.w;
    }
    base[(size_t)(blockIdx.x * 4 + 0) * EMBED + d] = a0;
    base[(size_t)(blockIdx.x * 4 + 1) * EMBED + d] = a1;
    base[(size_t)(blockIdx.x * 4 + 2) * EMBED + d] = a2;
    base[(size_t)(blockIdx.x * 4 + 3) * EMBED + d] = a3;
}

// ---- k2: out[t][e] = sum_d base[t][d] * T[rule][d][e] ----
// Block = (rule, 64-e slice); 256 thr = 64 e-lanes x 4 t-groups. Thread owns
// one e for ~12 tokens -> full d-sum in-thread, NO cross-wave reduction.
// T streamed from global exactly once per block (256 B coalesced rows,
// prefetched one d-quad ahead). base rows staged in 48 KB LDS; inner reads
// are wave-uniform b128 broadcasts.
__global__ __launch_bounds__(256) void apply_kernel(
    const float* __restrict__ base,           // [NTOK][EMBED] (ws)
    const float* __restrict__ rule_transform, // [NRULES][EMBED][EMBED]
    const int*   __restrict__ counts,         // [NRULES] (ws)
    const int*   __restrict__ list,           // [NRULES][CAP] (ws)
    float*       __restrict__ out)            // [NTOK][EMBED]
{
    __shared__ float s_base[TTILE * EMBED];   // 48 KB

    const int rule = blockIdx.x;
    int cnt = counts[rule];
    if (cnt > CAP) cnt = CAP;
    if (cnt <= 0) return;                     // uniform

    const int tid = threadIdx.x;
    const int el  = tid & 63;                 // e-lane
    const int tg  = tid >> 6;                 // t-group 0..3 (== wave id)
    const int e   = blockIdx.y * ETILE + el;

    const float* __restrict__ T   = rule_transform + (size_t)rule * EMBED * EMBED;
    const int*   __restrict__ lst = list + rule * CAP;

    for (int t0 = 0; t0 < cnt; t0 += TTILE) {
        // ---- stage up to 48 base rows (clamped tail), coalesced b128 ----
        __syncthreads();                      // protects LDS reuse across tiles
        for (int i = tid; i < TTILE * 64; i += 256) {
            const int t = i >> 6, c = i & 63; // t uniform per wave per iter
            int tt = t0 + t;
            if (tt > cnt - 1) tt = cnt - 1;   // pad with last row
            const int row = lst[tt];          // wave-uniform load
            ((float4*)s_base)[i] =
                ((const float4*)(base + (size_t)row * EMBED))[c];
        }
        __syncthreads();

        float acc[TPG];
        #pragma unroll
        for (int k = 0; k < TPG; ++k) acc[k] = 0.f;

        float tv[4], tvn[4];
        #pragma unroll
        for (int i = 0; i < 4; ++i)
            tv[i] = T[(size_t)i * EMBED + e];

        for (int dq = 0; dq < 64; ++dq) {
            if (dq < 63) {                    // prefetch next 4 T rows
                #pragma unroll
                for (int i = 0; i < 4; ++i)
                    tvn[i] = T[(size_t)((dq + 1) * 4 + i) * EMBED + e];
            }
            #pragma unroll
            for (int k = 0; k < TPG; ++k) {   // b128 broadcast per token
                const float4 b4 =
                    *(const float4*)&s_base[(k * 4 + tg) * EMBED + dq * 4];
                acc[k] += b4.x * tv[0] + b4.y * tv[1]
                        + b4.z * tv[2] + b4.w * tv[3];
            }
            #pragma unroll
            for (int i = 0; i < 4; ++i) tv[i] = tvn[i];
        }

        #pragma unroll
        for (int k = 0; k < TPG; ++k) {
            const int t = t0 + k * 4 + tg;
            if (t < cnt) {                    // wave-uniform predicate
                const int row = lst[t];
                out[(size_t)row * EMBED + e] = acc[k];  // 256 B coalesced
            }
        }
    }
}

extern "C" void kernel_launch(void* const* d_in, const int* in_sizes, int n_in,
                              void* d_out, int out_size, void* d_ws, size_t ws_size,
                              hipStream_t stream) {
    const int*   token_ids      = (const int*)  d_in[0];
    const float* a_n            = (const float*)d_in[1];
    const float* b_n            = (const float*)d_in[2];
    const float* rule_transform = (const float*)d_in[3];
    const int*   token_rules    = (const int*)  d_in[4];
    const float* proj_w         = (const float*)d_in[5];
    const float* proj_b         = (const float*)d_in[6];
    float*       out            = (float*)d_out;

    float* base   = (float*)d_ws;
    int*   counts = (int*)((char*)d_ws + BASE_BYTES);
    int*   list   = (int*)((char*)d_ws + BASE_BYTES + 512);
    float* wT     = (float*)((char*)d_ws + BASE_BYTES + 512 + LIST_BYTES);

    prep_kernel<<<4, 256, 0, stream>>>(proj_w, wT, counts);
    fused_base_kernel<<<NTOK / 4, 256, 0, stream>>>(
        token_ids, a_n, b_n, token_rules, wT, proj_b, base, counts, list);
    apply_kernel<<<dim3(NRULES, EMBED / ETILE), 256, 0, stream>>>(
        base, rule_transform, counts, list, out);
}

// Round 7
// 133.587 us; speedup vs baseline: 1.1893x; 1.1893x over previous
//
#include <hip/hip_runtime.h>
#include <math.h>

#define VOCAB   50257
#define EMBED   256
#define NFREQ   64
#define NRULES  100
#define NTOK    4096        // B*S
#define CAP     256         // max tokens per rule (mean 41, sd 6.4; P(>256)~0)
#define CHUNK   16          // tokens per apply-block
#define NCHUNK  (CAP / CHUNK)

// ---- workspace layout ----
// [0)                 : base   float[NTOK][EMBED]  (4 MB)
// [BASE_BYTES)        : counts int[NRULES]
// [BASE_BYTES+512)    : list   int[NRULES][CAP]    (100 KB)
// [BASE_BYTES+103424) : wT     float[NFREQ][EMBED] (64 KB)
#define BASE_BYTES ((size_t)NTOK * EMBED * 4)
#define LIST_BYTES ((size_t)NRULES * CAP * 4)

// ---- k0: transpose proj_w -> wT[f][d], zero counts. 4 blocks. ----
__global__ __launch_bounds__(256) void prep_kernel(
    const float* __restrict__ proj_w,   // [EMBED][NFREQ]
    float*       __restrict__ wT,       // [NFREQ][EMBED]
    int*         __restrict__ counts)   // [NRULES]
{
    __shared__ float s_t[64 * 65];      // padded transpose tile
    const int tid = threadIdx.x;
    const int b   = blockIdx.x;         // d-tile: rows [64b, 64b+64)

    if (b == 0 && tid < NRULES) counts[tid] = 0;

    const float4* __restrict__ W4 =
        (const float4*)(proj_w + (size_t)b * 64 * NFREQ);
    #pragma unroll
    for (int i = 0; i < 4; ++i) {
        const int v = i * 256 + tid;
        const float4 w = W4[v];         // coalesced b128
        const int dl = v >> 4, f0 = (v & 15) * 4;
        s_t[dl * 65 + f0 + 0] = w.x;
        s_t[dl * 65 + f0 + 1] = w.y;
        s_t[dl * 65 + f0 + 2] = w.z;
        s_t[dl * 65 + f0 + 3] = w.w;
    }
    __syncthreads();
    #pragma unroll
    for (int j = 0; j < 16; ++j) {
        const int o = j * 256 + tid;
        const int f = o >> 6, c = o & 63;
        wT[f * EMBED + b * 64 + c] = s_t[c * 65 + f];   // coalesced out
    }
}

// ---- k1: fourier + projection + bucketing. 1024 blocks x 256 thr ----
// 4 blocks/CU -> 4 waves/SIMD. wT read coalesced from global (L2-hot).
__global__ __launch_bounds__(256) void fused_base_kernel(
    const int*   __restrict__ token_ids,     // [NTOK]
    const float* __restrict__ a_n,           // [VOCAB][NFREQ]
    const float* __restrict__ b_n,           // [VOCAB][NFREQ]
    const int*   __restrict__ token_rules,   // [VOCAB]
    const float* __restrict__ wT,            // [NFREQ][EMBED] (ws)
    const float* __restrict__ proj_b,        // [EMBED]
    float*       __restrict__ base,          // [NTOK][EMBED] (ws)
    int*         __restrict__ counts,        // [NRULES] (ws, zeroed by prep)
    int*         __restrict__ list)          // [NRULES][CAP] (ws)
{
    __shared__ float s_four[4][NFREQ];       // 1 KB

    const int tid = threadIdx.x;
    const int tl  = tid >> 6;                // token 0..3
    const int f   = tid & 63;                // frequency lane
    const int tok_idx = blockIdx.x * 4 + tl;
    const int tok     = token_ids[tok_idx];

    const float x = (float)tok / (float)VOCAB;
    float sv, cv;
    sincosf(6.283185307179586f * x * (float)(f + 1), &sv, &cv);
    s_four[tl][f] = a_n[(size_t)tok * NFREQ + f] * cv
                  + b_n[(size_t)tok * NFREQ + f] * sv;   // coalesced gathers

    if (f == 0) {
        const int rule = token_rules[tok];
        const int pos  = atomicAdd(&counts[rule], 1);
        if (pos < CAP) list[rule * CAP + pos] = tok_idx;
    }
    __syncthreads();

    const int   d    = tid;
    const float bias = proj_b[d];
    float a0 = bias, a1 = bias, a2 = bias, a3 = bias;

    #pragma unroll 4
    for (int q = 0; q < 16; ++q) {
        const float w0 = wT[(4 * q + 0) * EMBED + d];   // coalesced, L2-hot
        const float w1 = wT[(4 * q + 1) * EMBED + d];
        const float w2 = wT[(4 * q + 2) * EMBED + d];
        const float w3 = wT[(4 * q + 3) * EMBED + d];
        const float4 f0 = ((const float4*)s_four[0])[q];
        const float4 f1 = ((const float4*)s_four[1])[q];
        const float4 f2 = ((const float4*)s_four[2])[q];
        const float4 f3 = ((const float4*)s_four[3])[q];
        a0 += w0 * f0.x + w1 * f0.y + w2 * f0.z + w3 * f0.w;
        a1 += w0 * f1.x + w1 * f1.y + w2 * f1.z + w3 * f1.w;
        a2 += w0 * f2.x + w1 * f2.y + w2 * f2.z + w3 * f2.w;
        a3 += w0 * f3.x + w1 * f3.y + w2 * f3.z + w3 * f3.w;
    }
    base[(size_t)(blockIdx.x * 4 + 0) * EMBED + d] = a0;
    base[(size_t)(blockIdx.x * 4 + 1) * EMBED + d] = a1;
    base[(size_t)(blockIdx.x * 4 + 2) * EMBED + d] = a2;
    base[(size_t)(blockIdx.x * 4 + 3) * EMBED + d] = a3;
}

// ---- k2: out[t][e] = sum_d base[t][d] * T[rule][d][e] ----
// Block = (rule, e-half, 16-token chunk): ~600 active blocks x 8 waves =
// 4800 waves (~4.7/SIMD). Wave = (d-slice 0..3, e-sub 0..1); thread owns one
// e column for 16 tokens. Serial chain: 16 dq iters, T prefetched 1 ahead.
// s_base[16][256] (16 KB) aliased with the reduce buffer.
__global__ __launch_bounds__(512) void apply_kernel(
    const float* __restrict__ base,           // [NTOK][EMBED] (ws)
    const float* __restrict__ rule_transform, // [NRULES][EMBED][EMBED]
    const int*   __restrict__ counts,         // [NRULES] (ws)
    const int*   __restrict__ list,           // [NRULES][CAP] (ws)
    float*       __restrict__ out)            // [NTOK][EMBED]
{
    __shared__ float s_mem[4096];             // 16 KB: s_base then s_red

    const int rule = blockIdx.x;
    const int eh   = blockIdx.y;              // e-half 0..1
    int cnt = counts[rule];
    if (cnt > CAP) cnt = CAP;
    const int t0 = blockIdx.z * CHUNK;
    if (t0 >= cnt) return;                    // uniform early-exit

    const int tid  = threadIdx.x;
    const int w8   = tid >> 6;                // wave 0..7
    const int ds   = w8 >> 1;                 // d-slice 0..3 (64 d each)
    const int es   = w8 & 1;                  // e-sub 0..1 (64 e each)
    const int lane = tid & 63;
    const int ec   = eh * 128 + es * 64 + lane;   // absolute e column

    const int* __restrict__ lst = list + rule * CAP;

    // stage s_base[16][256]: coalesced b128 global, conflict-free LDS
    #pragma unroll
    for (int i = 0; i < 2; ++i) {
        const int v = i * 512 + tid;          // float4 index 0..1023
        int tt = t0 + (v >> 6);
        if (tt > cnt - 1) tt = cnt - 1;       // pad tail with last token
        const int row = lst[tt];              // wave-uniform
        ((float4*)s_mem)[v] =
            ((const float4*)(base + (size_t)row * EMBED))[v & 63];
    }
    __syncthreads();

    const float* __restrict__ T =
        rule_transform + (size_t)rule * EMBED * EMBED;
    const int d0 = ds * 64;

    float acc[CHUNK];
    #pragma unroll
    for (int t = 0; t < CHUNK; ++t) acc[t] = 0.f;

    float tv[4], tvn[4];
    #pragma unroll
    for (int i = 0; i < 4; ++i)
        tv[i] = T[(size_t)(d0 + i) * EMBED + ec];

    for (int dq = 0; dq < 16; ++dq) {
        if (dq < 15) {                        // prefetch next 4 T rows
            #pragma unroll
            for (int i = 0; i < 4; ++i)
                tvn[i] = T[(size_t)(d0 + dq * 4 + 4 + i) * EMBED + ec];
        }
        #pragma unroll
        for (int t = 0; t < CHUNK; ++t) {     // broadcast b128 reads
            const float4 b4 = *(const float4*)&s_mem[t * EMBED + d0 + dq * 4];
            acc[t] += b4.x * tv[0] + b4.y * tv[1]
                    + b4.z * tv[2] + b4.w * tv[3];
        }
        #pragma unroll
        for (int i = 0; i < 4; ++i) tv[i] = tvn[i];
    }

    // ---- cross-slice reduce: (0+=1, 2+=3) then (0+=2); 1024 floats/region
    __syncthreads();                          // s_base dead, reuse s_mem
    if (ds == 1 || ds == 3) {
        float* dst = s_mem + ((ds >> 1) * 2 + es) * 1024;
        #pragma unroll
        for (int t = 0; t < CHUNK; ++t) dst[t * 64 + lane] = acc[t];
    }
    __syncthreads();
    if (ds == 0 || ds == 2) {
        const float* src = s_mem + ((ds >> 1) * 2 + es) * 1024;
        #pragma unroll
        for (int t = 0; t < CHUNK; ++t) acc[t] += src[t * 64 + lane];
    }
    __syncthreads();
    if (ds == 2) {
        float* dst = s_mem + es * 1024;
        #pragma unroll
        for (int t = 0; t < CHUNK; ++t) dst[t * 64 + lane] = acc[t];
    }
    __syncthreads();
    if (ds == 0) {
        const float* src = s_mem + es * 1024;
        #pragma unroll
        for (int t = 0; t < CHUNK; ++t) acc[t] += src[t * 64 + lane];
        #pragma unroll
        for (int t = 0; t < CHUNK; ++t) {
            if (t0 + t < cnt) {               // wave-uniform predicate
                const int row = lst[t0 + t];
                out[(size_t)row * EMBED + ec] = acc[t];   // 256 B coalesced
            }
        }
    }
}

extern "C" void kernel_launch(void* const* d_in, const int* in_sizes, int n_in,
                              void* d_out, int out_size, void* d_ws, size_t ws_size,
                              hipStream_t stream) {
    const int*   token_ids      = (const int*)  d_in[0];
    const float* a_n            = (const float*)d_in[1];
    const float* b_n            = (const float*)d_in[2];
    const float* rule_transform = (const float*)d_in[3];
    const int*   token_rules    = (const int*)  d_in[4];
    const float* proj_b         = (const float*)d_in[6];
    const float* proj_w         = (const float*)d_in[5];
    float*       out            = (float*)d_out;

    float* base   = (float*)d_ws;
    int*   counts = (int*)((char*)d_ws + BASE_BYTES);
    int*   list   = (int*)((char*)d_ws + BASE_BYTES + 512);
    float* wT     = (float*)((char*)d_ws + BASE_BYTES + 512 + LIST_BYTES);

    prep_kernel<<<4, 256, 0, stream>>>(proj_w, wT, counts);
    fused_base_kernel<<<NTOK / 4, 256, 0, stream>>>(
        token_ids, a_n, b_n, token_rules, wT, proj_b, base, counts, list);
    apply_kernel<<<dim3(NRULES, 2, NCHUNK), 512, 0, stream>>>(
        base, rule_transform, counts, list, out);
}

// Round 8
// 128.723 us; speedup vs baseline: 1.2342x; 1.0378x over previous
//
#include <hip/hip_runtime.h>
#include <math.h>

#define VOCAB   50257
#define EMBED   256
#define NFREQ   64
#define NRULES  100
#define NTOK    4096        // B*S
#define CAP     256         // max tokens per rule (mean 41, sd 6.4; P(>256)~0)
#define CHUNK   16          // tokens per apply-block
#define NCHUNK  (CAP / CHUNK)

// ---- workspace layout ----
// [0)                 : base   float[NTOK][EMBED]  (4 MB)
// [BASE_BYTES)        : counts int[NRULES]
// [BASE_BYTES+512)    : list   int[NRULES][CAP]    (100 KB)
// [BASE_BYTES+103424) : wT     float[NFREQ][EMBED] (64 KB)
#define BASE_BYTES ((size_t)NTOK * EMBED * 4)
#define LIST_BYTES ((size_t)NRULES * CAP * 4)

// ---- k0: transpose proj_w -> wT[f][d], zero counts. 4 blocks. ----
__global__ __launch_bounds__(256) void prep_kernel(
    const float* __restrict__ proj_w,   // [EMBED][NFREQ]
    float*       __restrict__ wT,       // [NFREQ][EMBED]
    int*         __restrict__ counts)   // [NRULES]
{
    __shared__ float s_t[64 * 65];      // padded transpose tile
    const int tid = threadIdx.x;
    const int b   = blockIdx.x;         // d-tile: rows [64b, 64b+64)

    if (b == 0 && tid < NRULES) counts[tid] = 0;

    const float4* __restrict__ W4 =
        (const float4*)(proj_w + (size_t)b * 64 * NFREQ);
    #pragma unroll
    for (int i = 0; i < 4; ++i) {
        const int v = i * 256 + tid;
        const float4 w = W4[v];         // coalesced b128
        const int dl = v >> 4, f0 = (v & 15) * 4;
        s_t[dl * 65 + f0 + 0] = w.x;
        s_t[dl * 65 + f0 + 1] = w.y;
        s_t[dl * 65 + f0 + 2] = w.z;
        s_t[dl * 65 + f0 + 3] = w.w;
    }
    __syncthreads();
    #pragma unroll
    for (int j = 0; j < 16; ++j) {
        const int o = j * 256 + tid;
        const int f = o >> 6, c = o & 63;
        wT[f * EMBED + b * 64 + c] = s_t[c * 65 + f];   // coalesced out
    }
}

// ---- k1: fourier + projection + bucketing. 1024 blocks x 256 thr ----
// HW v_sin/v_cos take REVOLUTIONS (ISA: D=sin(S0*2pi)); our angle is
// natively (f+1)*tok/VOCAB revolutions -> v_fract + v_sin, no libm.
__global__ __launch_bounds__(256) void fused_base_kernel(
    const int*   __restrict__ token_ids,     // [NTOK]
    const float* __restrict__ a_n,           // [VOCAB][NFREQ]
    const float* __restrict__ b_n,           // [VOCAB][NFREQ]
    const int*   __restrict__ token_rules,   // [VOCAB]
    const float* __restrict__ wT,            // [NFREQ][EMBED] (ws)
    const float* __restrict__ proj_b,        // [EMBED]
    float*       __restrict__ base,          // [NTOK][EMBED] (ws)
    int*         __restrict__ counts,        // [NRULES] (ws, zeroed by prep)
    int*         __restrict__ list)          // [NRULES][CAP] (ws)
{
    __shared__ float s_four[4][NFREQ];       // 1 KB

    const int tid = threadIdx.x;
    const int tl  = tid >> 6;                // token 0..3
    const int f   = tid & 63;                // frequency lane
    const int tok_idx = blockIdx.x * 4 + tl;
    const int tok     = token_ids[tok_idx];

    const float x   = (float)tok * (1.0f / (float)VOCAB);
    const float rev = (float)(f + 1) * x;          // angle in revolutions
    const float rf  = rev - floorf(rev);           // v_fract range reduction
    const float sv  = __builtin_amdgcn_sinf(rf);   // v_sin_f32
    const float cv  = __builtin_amdgcn_cosf(rf);   // v_cos_f32
    s_four[tl][f] = a_n[(size_t)tok * NFREQ + f] * cv
                  + b_n[(size_t)tok * NFREQ + f] * sv;   // coalesced gathers

    if (f == 0) {
        const int rule = token_rules[tok];
        const int pos  = atomicAdd(&counts[rule], 1);
        if (pos < CAP) list[rule * CAP + pos] = tok_idx;
    }
    __syncthreads();

    const int   d    = tid;
    const float bias = proj_b[d];
    float a0 = bias, a1 = bias, a2 = bias, a3 = bias;

    #pragma unroll 4
    for (int q = 0; q < 16; ++q) {
        const float w0 = wT[(4 * q + 0) * EMBED + d];   // coalesced, L2-hot
        const float w1 = wT[(4 * q + 1) * EMBED + d];
        const float w2 = wT[(4 * q + 2) * EMBED + d];
        const float w3 = wT[(4 * q + 3) * EMBED + d];
        const float4 f0 = ((const float4*)s_four[0])[q];
        const float4 f1 = ((const float4*)s_four[1])[q];
        const float4 f2 = ((const float4*)s_four[2])[q];
        const float4 f3 = ((const float4*)s_four[3])[q];
        a0 += w0 * f0.x + w1 * f0.y + w2 * f0.z + w3 * f0.w;
        a1 += w0 * f1.x + w1 * f1.y + w2 * f1.z + w3 * f1.w;
        a2 += w0 * f2.x + w1 * f2.y + w2 * f2.z + w3 * f2.w;
        a3 += w0 * f3.x + w1 * f3.y + w2 * f3.z + w3 * f3.w;
    }
    base[(size_t)(blockIdx.x * 4 + 0) * EMBED + d] = a0;
    base[(size_t)(blockIdx.x * 4 + 1) * EMBED + d] = a1;
    base[(size_t)(blockIdx.x * 4 + 2) * EMBED + d] = a2;
    base[(size_t)(blockIdx.x * 4 + 3) * EMBED + d] = a3;
}

// ---- k2: out[t][e] = sum_d base[t][d] * T[rule][d][e] ----
// Round-5 structure (best measured): block = (rule, 16-token chunk),
// 512 thr = 8 waves = 4 d-slices x 2 e-halves, thread owns an e-pair.
// New: T prefetch DEPTH 2 (covers ~500 cyc L2/L3 latency vs ~280 cyc body),
// b128 staging.
__global__ __launch_bounds__(512) void apply_kernel(
    const float* __restrict__ base,           // [NTOK][EMBED] (ws)
    const float* __restrict__ rule_transform, // [NRULES][EMBED][EMBED]
    const int*   __restrict__ counts,         // [NRULES] (ws)
    const int*   __restrict__ list,           // [NRULES][CAP] (ws)
    float*       __restrict__ out)            // [NTOK][EMBED]
{
    __shared__ float s_mem[8192];             // 32 KB: s_base[16][256] / s_red

    const int rule = blockIdx.x;
    int cnt = counts[rule];
    if (cnt > CAP) cnt = CAP;
    const int t0 = blockIdx.y * CHUNK;
    if (t0 >= cnt) return;                    // uniform early-exit

    const int tid  = threadIdx.x;
    const int w8   = tid >> 6;                // wave 0..7
    const int ds   = w8 >> 1;                 // d-slice 0..3 (64 d each)
    const int eh   = w8 & 1;                  // e-half 0..1 (128 e each)
    const int lane = tid & 63;

    const int* __restrict__ lst = list + rule * CAP;

    // stage s_base[16][256]: coalesced b128 global -> b128 LDS
    #pragma unroll
    for (int i = 0; i < 2; ++i) {
        const int v = i * 512 + tid;          // float4 index 0..1023
        int tt = t0 + (v >> 6);
        if (tt > cnt - 1) tt = cnt - 1;       // pad tail with last token
        const int row = lst[tt];              // wave-uniform
        ((float4*)s_mem)[v] =
            ((const float4*)(base + (size_t)row * EMBED))[v & 63];
    }
    __syncthreads();

    const float2* __restrict__ T2 =
        (const float2*)(rule_transform + (size_t)rule * EMBED * EMBED);
    const int d0 = ds * 64;
    const int ec = eh * 64 + lane;            // e-pair column index

    float2 acc[CHUNK];
    #pragma unroll
    for (int t = 0; t < CHUNK; ++t) { acc[t].x = 0.f; acc[t].y = 0.f; }

    // T pipeline: depth 2 (tv0 = current, tv1 = next, tvn = next-next)
    float2 tv0[4], tv1[4], tvn[4];
    #pragma unroll
    for (int i = 0; i < 4; ++i) tv0[i] = T2[(size_t)(d0 + i) * 128 + ec];
    #pragma unroll
    for (int i = 0; i < 4; ++i) tv1[i] = T2[(size_t)(d0 + 4 + i) * 128 + ec];

    for (int dq = 0; dq < 16; ++dq) {
        if (dq < 14) {                        // prefetch dq+2's 4 T rows
            #pragma unroll
            for (int i = 0; i < 4; ++i)
                tvn[i] = T2[(size_t)(d0 + (dq + 2) * 4 + i) * 128 + ec];
        }
        #pragma unroll
        for (int t = 0; t < CHUNK; ++t) {     // broadcast b128 reads
            const float4 b4 = *(const float4*)&s_mem[t * EMBED + d0 + dq * 4];
            acc[t].x += b4.x * tv0[0].x + b4.y * tv0[1].x
                      + b4.z * tv0[2].x + b4.w * tv0[3].x;
            acc[t].y += b4.x * tv0[0].y + b4.y * tv0[1].y
                      + b4.z * tv0[2].y + b4.w * tv0[3].y;
        }
        #pragma unroll
        for (int i = 0; i < 4; ++i) { tv0[i] = tv1[i]; tv1[i] = tvn[i]; }
    }

    // ---- cross-slice reduction: (0+=1, 2+=3) then (0+=2) ----
    __syncthreads();                          // s_base dead, reuse s_mem
    if (ds == 1 || ds == 3) {
        float2* dst = (float2*)(s_mem + ((ds >> 1) * 2 + eh) * 2048);
        #pragma unroll
        for (int t = 0; t < CHUNK; ++t) dst[t * 64 + lane] = acc[t];
    }
    __syncthreads();
    if (ds == 0 || ds == 2) {
        const float2* src = (const float2*)(s_mem + ((ds >> 1) * 2 + eh) * 2048);
        #pragma unroll
        for (int t = 0; t < CHUNK; ++t) {
            const float2 r = src[t * 64 + lane];
            acc[t].x += r.x; acc[t].y += r.y;
        }
    }
    __syncthreads();
    if (ds == 2) {
        float2* dst = (float2*)(s_mem + eh * 2048);
        #pragma unroll
        for (int t = 0; t < CHUNK; ++t) dst[t * 64 + lane] = acc[t];
    }
    __syncthreads();
    if (ds == 0) {
        const float2* src = (const float2*)(s_mem + eh * 2048);
        #pragma unroll
        for (int t = 0; t < CHUNK; ++t) {
            const float2 r = src[t * 64 + lane];
            acc[t].x += r.x; acc[t].y += r.y;
        }
        #pragma unroll
        for (int t = 0; t < CHUNK; ++t) {
            if (t0 + t < cnt) {
                const int row = lst[t0 + t];
                *(float2*)&out[(size_t)row * EMBED + eh * 128 + lane * 2] = acc[t];
            }
        }
    }
}

extern "C" void kernel_launch(void* const* d_in, const int* in_sizes, int n_in,
                              void* d_out, int out_size, void* d_ws, size_t ws_size,
                              hipStream_t stream) {
    const int*   token_ids      = (const int*)  d_in[0];
    const float* a_n            = (const float*)d_in[1];
    const float* b_n            = (const float*)d_in[2];
    const float* rule_transform = (const float*)d_in[3];
    const int*   token_rules    = (const int*)  d_in[4];
    const float* proj_w         = (const float*)d_in[5];
    const float* proj_b         = (const float*)d_in[6];
    float*       out            = (float*)d_out;

    float* base   = (float*)d_ws;
    int*   counts = (int*)((char*)d_ws + BASE_BYTES);
    int*   list   = (int*)((char*)d_ws + BASE_BYTES + 512);
    float* wT     = (float*)((char*)d_ws + BASE_BYTES + 512 + LIST_BYTES);

    prep_kernel<<<4, 256, 0, stream>>>(proj_w, wT, counts);
    fused_base_kernel<<<NTOK / 4, 256, 0, stream>>>(
        token_ids, a_n, b_n, token_rules, wT, proj_b, base, counts, list);
    apply_kernel<<<dim3(NRULES, NCHUNK), 512, 0, stream>>>(
        base, rule_transform, counts, list, out);
}